// Round 7
// baseline (417.339 us; speedup 1.0000x reference)
//
#include <hip/hip_runtime.h>

#define U 20

struct Ptrs { const float* p[16]; };

// LDS element offsets (floats). All matrix bases are mult-of-4 (16B aligned).
#define W1A 0
#define B1A 48
#define W1B 64      // 16x32
#define B1B 576
#define W1C 608     // 32x16
#define B1C 1120
#define W1D 1136    // 16x19
#define B1D 1440
#define W2A 1460
#define B2A 1508
#define W2B 1524    // 16x32
#define B2B 2036
#define W2C 2068    // 32x16
#define B2C 2580
#define W2D 2596    // 16x186 restrided to 16x188
#define B2D (W2D + 16*188)      // 5604, len 186 -> end 5790
#define NW   5792
#define H2O  NW                  // per-thread h2 scratch: 64 rows, stride 33
#define LDSZ (NW + 64*33)        // 7904 floats = 31616 B -> 5 blocks/CU

// One wave per block, one thread per (b,i); 1280 blocks = 5 waves/CU.
// Weights live in LDS (broadcast ds_reads, rolled loops -> tiny code).
// Each thread zeroes its own output row immediately before overwriting the
// band -> L2 absorbs the double-write; HBM sees ~278 MB once.
__launch_bounds__(64)
__global__ void fused(const float* __restrict__ x, Ptrs pt,
                      float* __restrict__ out, int B, int total) {
    __shared__ float lds[LDSZ];
    const int tid = threadIdx.x;
    const int t   = blockIdx.x * 64 + tid;

    // ---- cooperative weight load into LDS ----
    {
        const int lens[16] = {48,16,512,32,512,16,304,19,48,16,512,32,512,16,2976,186};
        const int offs[16] = {W1A,B1A,W1B,B1B,W1C,B1C,W1D,B1D,W2A,B2A,W2B,B2B,W2C,B2C,W2D,B2D};
        for (int a = 0; a < 16; a++) {
            const float* s = pt.p[a];
            const int len = lens[a], off = offs[a];
            if (a == 14) {
                for (int e = tid; e < len; e += 64) {
                    int k = e / 186, n = e - k * 186;
                    lds[off + k * 188 + n] = s[e];
                }
            } else {
                for (int e = tid; e < len; e += 64) lds[off + e] = s[e];
            }
        }
    }
    __syncthreads();
    if (t >= total) return;

    const int b = t / U;
    const int i = t - b * U;

    const float* xb = x + (size_t)b * U;
    const int im = (i == 0)     ? U - 1 : i - 1;
    const int ip = (i == U - 1) ? 0     : i + 1;
    const float v0 = xb[im], v1 = xb[i], v2 = xb[ip];

    const size_t g1_off = (size_t)B * 20;
    const size_t f2_off = (size_t)B * 2420;
    const size_t g2_off = (size_t)B * 2540;
    float* g1row  = out + g1_off + (size_t)t * 120;
    float* g2rows = out + g2_off + (size_t)t * 720;
    float* hrow   = lds + H2O + tid * 33;

    float4 z4; z4.x = z4.y = z4.z = z4.w = 0.f;
    float h1[16], h3[16];

    // =========== macro: 3-layer trunk -> h3 regs ===========
#define TRUNK(wA,bA,wB,bB,wC,bC)                                              \
    {                                                                         \
        _Pragma("unroll")                                                     \
        for (int n = 0; n < 16; n++)                                          \
            h1[n] = fmaxf(lds[(bA)+n] + v0*lds[(wA)+n] + v1*lds[(wA)+16+n]    \
                          + v2*lds[(wA)+32+n], 0.f);                          \
        _Pragma("unroll 1")                                                   \
        for (int n = 0; n < 32; n += 4) {                                     \
            float a0 = lds[(bB)+n], a1 = lds[(bB)+n+1];                       \
            float a2 = lds[(bB)+n+2], a3 = lds[(bB)+n+3];                     \
            _Pragma("unroll")                                                 \
            for (int k = 0; k < 16; k++) {                                    \
                const float4 wv = *reinterpret_cast<const float4*>(           \
                    &lds[(wB) + k*32 + n]);                                   \
                a0 += h1[k]*wv.x; a1 += h1[k]*wv.y;                           \
                a2 += h1[k]*wv.z; a3 += h1[k]*wv.w;                           \
            }                                                                 \
            hrow[n]   = fmaxf(a0, 0.f); hrow[n+1] = fmaxf(a1, 0.f);           \
            hrow[n+2] = fmaxf(a2, 0.f); hrow[n+3] = fmaxf(a3, 0.f);           \
        }                                                                     \
        _Pragma("unroll")                                                     \
        for (int n = 0; n < 16; n++) h3[n] = lds[(bC)+n];                     \
        _Pragma("unroll 1")                                                   \
        for (int k = 0; k < 32; k++) {                                        \
            const float hk = hrow[k];                                         \
            const float4* wr = reinterpret_cast<const float4*>(               \
                &lds[(wC) + k*16]);                                           \
            _Pragma("unroll")                                                 \
            for (int q = 0; q < 4; q++) {                                     \
                const float4 wv = wr[q];                                      \
                h3[4*q]   += hk*wv.x; h3[4*q+1] += hk*wv.y;                   \
                h3[4*q+2] += hk*wv.z; h3[4*q+3] += hk*wv.w;                   \
            }                                                                 \
        }                                                                     \
        _Pragma("unroll")                                                     \
        for (int n = 0; n < 16; n++) h3[n] = fmaxf(h3[n], 0.f);               \
    }

    // ================= MLP 1 =================
    TRUNK(W1A, B1A, W1B, B1B, W1C, B1C)

    {   // zero own g1 row, then f1 + band stores (rolled over 19 outputs)
        float4* d = reinterpret_cast<float4*>(g1row);
        #pragma unroll
        for (int m = 0; m < 30; m++) d[m] = z4;
        #pragma unroll 1
        for (int n = 0; n < 19; n++) {
            float acc = lds[B1D + n];
            #pragma unroll
            for (int k = 0; k < 16; k++) acc += h3[k] * lds[W1D + k*19 + n];
            if (n == 0) {
                out[t] = acc;                       // f1
            } else {
                int m = n - 1;
                int j = m / 6, r = m - j * 6;
                int cc = i - 1 + j; if (cc < 0) cc += U; if (cc >= U) cc -= U;
                g1row[cc * 6 + r] = acc;
            }
        }
    }

    // ================= MLP 2 =================
    TRUNK(W2A, B2A, W2B, B2B, W2C, B2C)

    // f2: outputs 0..5
    #pragma unroll 1
    for (int n = 0; n < 6; n++) {
        float acc = lds[B2D + n];
        #pragma unroll
        for (int k = 0; k < 16; k++) acc += h3[k] * lds[W2D + k*188 + n];
        out[f2_off + (size_t)t * 6 + n] = acc;
    }

    // g2: per z, zero own row then 15 output-pairs -> band stores
    #pragma unroll 1
    for (int z = 0; z < 6; z++) {
        float* row = g2rows + z * 120;
        float4* rv = reinterpret_cast<float4*>(row);
        #pragma unroll
        for (int m = 0; m < 30; m++) rv[m] = z4;
        const int nb = 6 + z * 30;
        #pragma unroll 1
        for (int p = 0; p < 15; p++) {
            const int n = nb + 2 * p;
            float a0 = lds[B2D + n], a1 = lds[B2D + n + 1];
            #pragma unroll
            for (int k = 0; k < 16; k++) {
                const float2 wv = *reinterpret_cast<const float2*>(
                    &lds[W2D + k*188 + n]);
                a0 += h3[k] * wv.x; a1 += h3[k] * wv.y;
            }
            const int r = 2 * p;
            const int j = r / 6, m2 = r - j * 6;
            int cc = i - 2 + j; if (cc < 0) cc += U; if (cc >= U) cc -= U;
            float2 v; v.x = a0; v.y = a1;
            *reinterpret_cast<float2*>(row + cc * 6 + m2) = v;
        }
    }
#undef TRUNK
}

extern "C" void kernel_launch(void* const* d_in, const int* in_sizes, int n_in,
                              void* d_out, int out_size, void* d_ws, size_t ws_size,
                              hipStream_t stream) {
    const float* x = (const float*)d_in[0];
    Ptrs pt;
    for (int a = 0; a < 16; a++) pt.p[a] = (const float*)d_in[1 + a];

    int total = in_sizes[0];      // B * 20
    int B = total / U;

    int blocks = (total + 63) / 64;
    fused<<<blocks, 64, 0, stream>>>(x, pt, (float*)d_out, B, total);
}